// Round 6
// baseline (1391.660 us; speedup 1.0000x reference)
//
#include <hip/hip_runtime.h>
#include <hip/hip_cooperative_groups.h>
#include <stdint.h>

namespace cg = cooperative_groups;

#define N_NODES 40000
#define N_EDGES 640000
#define DD 128
#define LAYERS 3
#define SB 40     // scan blocks
#define GRID 625  // 625 * 64 rows = 40000
#define BLK 256

typedef unsigned short u16;
typedef u16 u16x8 __attribute__((ext_vector_type(8)));
typedef short bf16x8 __attribute__((ext_vector_type(8)));
typedef float f32x4 __attribute__((ext_vector_type(4)));

__device__ inline u16 f2bf(float f) {  // RNE f32 -> bf16 (finite inputs)
  uint32_t u = __float_as_uint(f);
  return (u16)((u + 0x7fffu + ((u >> 16) & 1u)) >> 16);
}
__device__ inline float bflo2f(uint32_t u) { return __uint_as_float(u << 16); }
__device__ inline float bfhi2f(uint32_t u) { return __uint_as_float(u & 0xffff0000u); }

struct Params {
  const float* x_in;
  const int* e_src;
  const int* e_dst;
  const float* psi_w;
  const float* psi_b;
  const float* phi_w;
  const float* phi_b;
  const float* dp_w;
  const float* dp_b;
  float* out;
  int* deg;  // cnt = deg + N_NODES (contiguous)
  int* offs;
  int* csr;
  float* inv_deg;
  u16* xb0;
  u16* xb1;
  u16* Ab;
  u16* Bb;
  u16* aggb;
  u16* psiF;
  u16* phiT;
  u16* dpT;
};

union SMem {
  struct { u16 Xs[64][72]; u16 Ws[256][72]; } psi;    // 46080 B
  struct { u16 Xs[2][64][72]; u16 Ws[128][72]; } phi; // 36864 B
  int red[256];
};

// ---------------- phase: setup (zero deg/cnt, convert x + weights, sentinels) ----------------

__device__ __forceinline__ void phase_setup(const Params& p) {
  int tg = blockIdx.x * BLK + threadIdx.x;  // 0..159999
  if (tg < 20000) *(int4*)(p.deg + tg * 4) = (int4){0, 0, 0, 0};  // deg + cnt (80000 ints)
  else if (tg < 20064) ((uint32_t*)(p.Bb + (size_t)N_NODES * DD))[tg - 20000] = 0xFF80FF80u;
  else if (tg < 20072) p.csr[N_EDGES + (tg - 20064)] = N_NODES;  // sentinel pad
  // convert x: 640000 vec8 = 4 sweeps
#pragma unroll
  for (int s = 0; s < 4; ++s) {
    size_t i = ((size_t)tg + (size_t)s * 160000) * 8;
    float4 v0 = *(const float4*)(p.x_in + i);
    float4 v1 = *(const float4*)(p.x_in + i + 4);
    u16x8 o;
    o[0] = f2bf(v0.x); o[1] = f2bf(v0.y); o[2] = f2bf(v0.z); o[3] = f2bf(v0.w);
    o[4] = f2bf(v1.x); o[5] = f2bf(v1.y); o[6] = f2bf(v1.z); o[7] = f2bf(v1.w);
    *(u16x8*)(p.xb0 + i) = o;
  }
  // weights: psiF [l][o=256][k=128]; phiT [l][n=128][k=256]; dpT [n=128][k=128]
#pragma unroll
  for (int s = 0; s < 2; ++s) {
    int idx = tg + s * 160000;
    if (idx < 98304) {
      int l = idx >> 15, r = idx & 32767, o = r >> 7, k = r & 127;
      int kk = k + ((o >= 128) ? 128 : 0);
      p.psiF[idx] = f2bf(p.psi_w[l * 32768 + kk * 128 + (o & 127)]);
    } else if (idx < 196608) {
      int j = idx - 98304;
      int l = j >> 15, r = j & 32767, n = r >> 8, k = r & 255;
      p.phiT[j] = f2bf(p.phi_w[l * 32768 + k * 128 + n]);
    } else if (idx < 212992) {
      int j = idx - 196608;
      int n = j >> 7, k = j & 127;
      p.dpT[j] = f2bf(p.dp_w[k * 128 + n]);
    }
  }
}

// ---------------- phase: count degrees ----------------

__device__ __forceinline__ void phase_count(const Params& p) {
  int tg = blockIdx.x * BLK + threadIdx.x;
#pragma unroll
  for (int s = 0; s < 4; ++s) atomicAdd(&p.deg[p.e_dst[tg + s * 160000]], 1);
}

// ---------------- phase: scan (offs + inv_deg); blocks 0..39 only ----------------

__device__ __forceinline__ void phase_scan(const Params& p, int* red) {
  int b = blockIdx.x;
  if (b >= SB) return;
  int t = threadIdx.x;
  int base_n = b * 1024;
  int loc = 0;
  for (int i = t * 4; i < base_n; i += 1024) {
    int4 v = *(const int4*)(p.deg + i);
    loc += v.x + v.y + v.z + v.w;
  }
  red[t] = loc;
  __syncthreads();
  for (int o = 128; o > 0; o >>= 1) {
    if (t < o) red[t] += red[t + o];
    __syncthreads();
  }
  int base = red[0];
  __syncthreads();
  int idx = base_n + t * 4;
  int4 v = {0, 0, 0, 0};
  if (idx < N_NODES) v = *(const int4*)(p.deg + idx);
  int ts = v.x + v.y + v.z + v.w;
  red[t] = ts;
  __syncthreads();
  for (int o = 1; o < 256; o <<= 1) {
    int u = (t >= o) ? red[t - o] : 0;
    __syncthreads();
    red[t] += u;
    __syncthreads();
  }
  int excl = base + red[t] - ts;
  if (idx < N_NODES) {
    int4 ov;
    ov.x = excl;
    ov.y = excl + v.x;
    ov.z = ov.y + v.y;
    ov.w = ov.z + v.z;
    *(int4*)(p.offs + idx) = ov;
    float4 iv;
    iv.x = 1.0f / (float)(v.x > 1 ? v.x : 1);
    iv.y = 1.0f / (float)(v.y > 1 ? v.y : 1);
    iv.z = 1.0f / (float)(v.z > 1 ? v.z : 1);
    iv.w = 1.0f / (float)(v.w > 1 ? v.w : 1);
    *(float4*)(p.inv_deg + idx) = iv;
  }
  if (b == SB - 1 && t == 255) p.offs[N_NODES] = base + red[255];
}

// ---------------- phase: fill CSR ----------------

__device__ __forceinline__ void phase_fill(const Params& p) {
  int tg = blockIdx.x * BLK + threadIdx.x;
  int* cnt = p.deg + N_NODES;
#pragma unroll
  for (int s = 0; s < 4; ++s) {
    int e = tg + s * 160000;
    int d = p.e_dst[e];
    int pos = p.offs[d] + atomicAdd(&cnt[d], 1);
    p.csr[pos] = p.e_src[e];
  }
}

// ---------------- phase: psi GEMM [Ab|Bb] = X @ Wf[128x256] ----------------

__device__ __forceinline__ void phase_psi(SMem& sm, const u16* __restrict__ X0,
                                          const u16* __restrict__ Wf,
                                          const float* __restrict__ bias,
                                          u16* __restrict__ Ab, u16* __restrict__ Bb) {
  const int tid = threadIdx.x;
  const int row0 = blockIdx.x * 64;
  const int w = tid >> 6, lane = tid & 63;
  const int lm = lane & 15, lq = lane >> 4;

  f32x4 acc[16];
#pragma unroll
  for (int i = 0; i < 16; ++i) acc[i] = (f32x4){0.f, 0.f, 0.f, 0.f};

#pragma unroll
  for (int c = 0; c < 2; ++c) {
#pragma unroll
    for (int i = 0; i < 2; ++i) {
      int fi = tid + i * 256;
      int r = fi >> 3, k8 = (fi & 7) * 8;
      *(u16x8*)&sm.psi.Xs[r][k8] = *(const u16x8*)(X0 + (size_t)(row0 + r) * DD + c * 64 + k8);
    }
#pragma unroll
    for (int i = 0; i < 8; ++i) {
      int fi = tid + i * 256;
      int n = fi >> 3, k8 = (fi & 7) * 8;
      *(u16x8*)&sm.psi.Ws[n][k8] = *(const u16x8*)(Wf + (size_t)n * 128 + c * 64 + k8);
    }
    __syncthreads();
#pragma unroll
    for (int ks = 0; ks < 2; ++ks) {
      bf16x8 a = *(const bf16x8*)&sm.psi.Xs[w * 16 + lm][lq * 8 + ks * 32];
#pragma unroll
      for (int nt = 0; nt < 16; ++nt) {
        bf16x8 b = *(const bf16x8*)&sm.psi.Ws[nt * 16 + lm][lq * 8 + ks * 32];
        acc[nt] = __builtin_amdgcn_mfma_f32_16x16x32_bf16(a, b, acc[nt], 0, 0, 0);
      }
    }
    __syncthreads();
  }

  float bj[8];
#pragma unroll
  for (int nt = 0; nt < 8; ++nt) bj[nt] = bias[nt * 16 + lm];
#pragma unroll
  for (int r = 0; r < 4; ++r) {
    size_t grow = (size_t)(row0 + w * 16 + lq * 4 + r) * DD;
#pragma unroll
    for (int nt = 0; nt < 8; ++nt) Ab[grow + nt * 16 + lm] = f2bf(acc[nt][r] + bj[nt]);
#pragma unroll
    for (int nt = 0; nt < 8; ++nt) Bb[grow + nt * 16 + lm] = f2bf(acc[nt + 8][r]);
  }
}

// ---------------- phase: aggregate (2500 waves, 2 nodes concurrent, 8 gathers each) ----------

__device__ __forceinline__ void phase_agg(const Params& p) {
  int wid = blockIdx.x * 4 + (threadIdx.x >> 6);  // 0..2499
  int lane = threadIdx.x & 63;
  const int c2 = lane * 2;
  int nb = wid * 16;
  for (int j = 0; j < 16; j += 2) {
    int n0 = nb + j, n1 = n0 + 1;
    uint32_t a0 = *(const uint32_t*)(p.Ab + (size_t)n0 * DD + c2);
    uint32_t a1 = *(const uint32_t*)(p.Ab + (size_t)n1 * DD + c2);
    float ax0 = bflo2f(a0), ay0 = bfhi2f(a0);
    float ax1 = bflo2f(a1), ay1 = bfhi2f(a1);
    int e0 = p.offs[n0], ee0 = p.offs[n0 + 1];
    int e1 = ee0, ee1 = p.offs[n1 + 1];
    float sx0 = 0.f, sy0 = 0.f, sx1 = 0.f, sy1 = 0.f;
    while (e0 < ee0 || e1 < ee1) {
      int s0[8], s1[8];
#pragma unroll
      for (int i = 0; i < 8; ++i) {
        int v0 = p.csr[e0 + i];  // csr padded with 8 sentinels
        s0[i] = (e0 + i < ee0) ? v0 : N_NODES;
        int v1 = p.csr[e1 + i];
        s1[i] = (e1 + i < ee1) ? v1 : N_NODES;
      }
      uint32_t bv0[8], bv1[8];
#pragma unroll
      for (int i = 0; i < 8; ++i) {
        bv0[i] = *(const uint32_t*)(p.Bb + (size_t)s0[i] * DD + c2);
        bv1[i] = *(const uint32_t*)(p.Bb + (size_t)s1[i] * DD + c2);
      }
#pragma unroll
      for (int i = 0; i < 8; ++i) {
        sx0 += fmaxf(ax0 + bflo2f(bv0[i]), 0.f);
        sy0 += fmaxf(ay0 + bfhi2f(bv0[i]), 0.f);
        sx1 += fmaxf(ax1 + bflo2f(bv1[i]), 0.f);
        sy1 += fmaxf(ay1 + bfhi2f(bv1[i]), 0.f);
      }
      e0 = (e0 + 8 < ee0) ? e0 + 8 : ee0;
      e1 = (e1 + 8 < ee1) ? e1 + 8 : ee1;
    }
    float w0 = p.inv_deg[n0], w1 = p.inv_deg[n1];
    uint32_t o0 = (uint32_t)f2bf(sx0 * w0) | ((uint32_t)f2bf(sy0 * w0) << 16);
    uint32_t o1 = (uint32_t)f2bf(sx1 * w1) | ((uint32_t)f2bf(sy1 * w1) << 16);
    *(uint32_t*)(p.aggb + (size_t)n0 * DD + c2) = o0;
    *(uint32_t*)(p.aggb + (size_t)n1 * DD + c2) = o1;
  }
}

// ---------------- phase: phi GEMM (K=256: x|agg) + residual; LAST: + dp GEMM -> fp32 out ----

__device__ __forceinline__ void phase_phi(SMem& sm, const Params& p, const u16* __restrict__ X0,
                                          const u16* __restrict__ Wt,
                                          const float* __restrict__ bias, u16* __restrict__ outB,
                                          bool last) {
  const int tid = threadIdx.x;
  const int row0 = blockIdx.x * 64;
  const int w = tid >> 6, lane = tid & 63;
  const int lm = lane & 15, lq = lane >> 4;

  f32x4 acc[8];
#pragma unroll
  for (int i = 0; i < 8; ++i) acc[i] = (f32x4){0.f, 0.f, 0.f, 0.f};

#pragma unroll
  for (int c = 0; c < 4; ++c) {
    const u16* Xsrc = (c < 2) ? (X0 + c * 64) : (p.aggb + (c - 2) * 64);
#pragma unroll
    for (int i = 0; i < 2; ++i) {
      int fi = tid + i * 256;
      int r = fi >> 3, k8 = (fi & 7) * 8;
      *(u16x8*)&sm.phi.Xs[c & 1][r][k8] = *(const u16x8*)(Xsrc + (size_t)(row0 + r) * DD + k8);
    }
#pragma unroll
    for (int i = 0; i < 4; ++i) {
      int fi = tid + i * 256;
      int n = fi >> 3, k8 = (fi & 7) * 8;
      *(u16x8*)&sm.phi.Ws[n][k8] = *(const u16x8*)(Wt + (size_t)n * 256 + c * 64 + k8);
    }
    __syncthreads();
#pragma unroll
    for (int ks = 0; ks < 2; ++ks) {
      bf16x8 a = *(const bf16x8*)&sm.phi.Xs[c & 1][w * 16 + lm][lq * 8 + ks * 32];
#pragma unroll
      for (int nt = 0; nt < 8; ++nt) {
        bf16x8 b = *(const bf16x8*)&sm.phi.Ws[nt * 16 + lm][lq * 8 + ks * 32];
        acc[nt] = __builtin_amdgcn_mfma_f32_16x16x32_bf16(a, b, acc[nt], 0, 0, 0);
      }
    }
    __syncthreads();
  }

  float bj[8];
#pragma unroll
  for (int nt = 0; nt < 8; ++nt) bj[nt] = bias[nt * 16 + lm];
#pragma unroll
  for (int r = 0; r < 4; ++r) {
    int lrow = w * 16 + lq * 4 + r;
    size_t grow = (size_t)(row0 + lrow) * DD;
#pragma unroll
    for (int nt = 0; nt < 8; ++nt) {
      float res = bflo2f((uint32_t)X0[grow + nt * 16 + lm]);
      float v = fmaxf(acc[nt][r] + bj[nt], 0.f) + res;
      if (!last) {
        outB[grow + nt * 16 + lm] = f2bf(v);
      } else {
        sm.phi.Xs[nt >> 2][lrow][(nt & 3) * 16 + lm] = f2bf(v);
      }
    }
  }

  if (last) {
    __syncthreads();
    f32x4 acc2[8];
#pragma unroll
    for (int i = 0; i < 8; ++i) acc2[i] = (f32x4){0.f, 0.f, 0.f, 0.f};
#pragma unroll
    for (int c = 0; c < 2; ++c) {
#pragma unroll
      for (int i = 0; i < 4; ++i) {
        int fi = tid + i * 256;
        int n = fi >> 3, k8 = (fi & 7) * 8;
        *(u16x8*)&sm.phi.Ws[n][k8] = *(const u16x8*)(p.dpT + (size_t)n * DD + c * 64 + k8);
      }
      __syncthreads();
#pragma unroll
      for (int ks = 0; ks < 2; ++ks) {
        bf16x8 a = *(const bf16x8*)&sm.phi.Xs[c][w * 16 + lm][lq * 8 + ks * 32];
#pragma unroll
        for (int nt = 0; nt < 8; ++nt) {
          bf16x8 b = *(const bf16x8*)&sm.phi.Ws[nt * 16 + lm][lq * 8 + ks * 32];
          acc2[nt] = __builtin_amdgcn_mfma_f32_16x16x32_bf16(a, b, acc2[nt], 0, 0, 0);
        }
      }
      __syncthreads();
    }
    float dj[8];
#pragma unroll
    for (int nt = 0; nt < 8; ++nt) dj[nt] = p.dp_b[nt * 16 + lm];
#pragma unroll
    for (int r = 0; r < 4; ++r) {
      size_t grow = (size_t)(row0 + w * 16 + lq * 4 + r) * DD;
#pragma unroll
      for (int nt = 0; nt < 8; ++nt) p.out[grow + nt * 16 + lm] = acc2[nt][r] + dj[nt];
    }
  }
}

// ---------------- mega kernel (cooperative) ----------------

__global__ void __launch_bounds__(256, 3) mpnn_mega(Params p) {
  cg::grid_group grid = cg::this_grid();
  __shared__ SMem sm;

  phase_setup(p);
  grid.sync();
  phase_count(p);
  grid.sync();
  phase_scan(p, sm.red);
  grid.sync();
  phase_fill(p);
  grid.sync();

  for (int l = 0; l < LAYERS; ++l) {
    const u16* xc = (l == 1) ? p.xb1 : p.xb0;
    u16* xn = (l == 0) ? p.xb1 : p.xb0;
    phase_psi(sm, xc, p.psiF + (size_t)l * 32768, p.psi_b + l * DD, p.Ab, p.Bb);
    grid.sync();
    phase_agg(p);
    grid.sync();
    phase_phi(sm, p, xc, p.phiT + (size_t)l * 32768, p.phi_b + l * DD, xn, l == LAYERS - 1);
    if (l < LAYERS - 1) grid.sync();
  }
}

// ---------------- fallback kernels (non-cooperative path) ----------------

__global__ void __launch_bounds__(256, 3) k_setup(Params p) { phase_setup(p); }
__global__ void __launch_bounds__(256, 3) k_count(Params p) { phase_count(p); }
__global__ void __launch_bounds__(256, 3) k_scan(Params p) {
  __shared__ SMem sm;
  phase_scan(p, sm.red);
}
__global__ void __launch_bounds__(256, 3) k_fill(Params p) { phase_fill(p); }
__global__ void __launch_bounds__(256, 3) k_psi(Params p, int l) {
  __shared__ SMem sm;
  const u16* xc = (l == 1) ? p.xb1 : p.xb0;
  phase_psi(sm, xc, p.psiF + (size_t)l * 32768, p.psi_b + l * DD, p.Ab, p.Bb);
}
__global__ void __launch_bounds__(256, 3) k_agg(Params p) { phase_agg(p); }
__global__ void __launch_bounds__(256, 3) k_phi(Params p, int l) {
  __shared__ SMem sm;
  const u16* xc = (l == 1) ? p.xb1 : p.xb0;
  u16* xn = (l == 0) ? p.xb1 : p.xb0;
  phase_phi(sm, p, xc, p.phiT + (size_t)l * 32768, p.phi_b + l * DD, xn, l == LAYERS - 1);
}

// ---------------- launch ----------------

static inline char* align256(char* p) {
  return (char*)(((uintptr_t)p + 255) & ~(uintptr_t)255);
}

extern "C" void kernel_launch(void* const* d_in, const int* in_sizes, int n_in,
                              void* d_out, int out_size, void* d_ws, size_t ws_size,
                              hipStream_t stream) {
  const size_t NF = (size_t)N_NODES * DD;

  char* p = (char*)d_ws;
  int* deg = (int*)p;         p += 2 * N_NODES * sizeof(int);  // deg + cnt contiguous
  p = align256(p);
  int* offs = (int*)p;        p = align256(p + (N_NODES + 1) * sizeof(int));
  int* csr = (int*)p;         p = align256(p + (N_EDGES + 8) * sizeof(int));
  float* inv_deg = (float*)p; p = align256(p + N_NODES * sizeof(float));
  u16* xb0 = (u16*)p;         p = align256(p + NF * sizeof(u16));
  u16* xb1 = (u16*)p;         p = align256(p + NF * sizeof(u16));
  u16* Ab = (u16*)p;          p = align256(p + NF * sizeof(u16));
  u16* Bb = (u16*)p;          p = align256(p + (NF + DD) * sizeof(u16));  // +1 sentinel row
  u16* aggb = (u16*)p;        p = align256(p + NF * sizeof(u16));
  u16* psiF = (u16*)p;        p = align256(p + 3 * 256 * 128 * sizeof(u16));
  u16* phiT = (u16*)p;        p = align256(p + 3 * 128 * 256 * sizeof(u16));
  u16* dpT = (u16*)p;         p = align256(p + 128 * 128 * sizeof(u16));

  Params prm;
  prm.x_in = (const float*)d_in[0];
  prm.e_src = (const int*)d_in[1];
  prm.e_dst = (const int*)d_in[1] + N_EDGES;
  prm.psi_w = (const float*)d_in[2];
  prm.psi_b = (const float*)d_in[3];
  prm.phi_w = (const float*)d_in[4];
  prm.phi_b = (const float*)d_in[5];
  prm.dp_w = (const float*)d_in[6];
  prm.dp_b = (const float*)d_in[7];
  prm.out = (float*)d_out;
  prm.deg = deg;
  prm.offs = offs;
  prm.csr = csr;
  prm.inv_deg = inv_deg;
  prm.xb0 = xb0;
  prm.xb1 = xb1;
  prm.Ab = Ab;
  prm.Bb = Bb;
  prm.aggb = aggb;
  prm.psiF = psiF;
  prm.phiT = phiT;
  prm.dpT = dpT;

  void* args[] = {&prm};
  hipError_t err = hipLaunchCooperativeKernel((const void*)mpnn_mega, dim3(GRID), dim3(BLK),
                                              args, 0, stream);
  if (err != hipSuccess) {
    (void)hipGetLastError();  // clear error, take non-cooperative path
    k_setup<<<GRID, BLK, 0, stream>>>(prm);
    k_count<<<GRID, BLK, 0, stream>>>(prm);
    k_scan<<<SB, BLK, 0, stream>>>(prm);
    k_fill<<<GRID, BLK, 0, stream>>>(prm);
    for (int l = 0; l < LAYERS; ++l) {
      k_psi<<<GRID, BLK, 0, stream>>>(prm, l);
      k_agg<<<GRID, BLK, 0, stream>>>(prm);
      k_phi<<<GRID, BLK, 0, stream>>>(prm, l);
    }
  }
}

// Round 7
// 287.907 us; speedup vs baseline: 4.8337x; 4.8337x over previous
//
#include <hip/hip_runtime.h>
#include <stdint.h>

#define N_NODES 40000
#define N_EDGES 640000
#define DD 128
#define LAYERS 3
#define SB 40  // scan blocks: 40 * 1024 >= N_NODES

typedef unsigned short u16;
typedef u16 u16x8 __attribute__((ext_vector_type(8)));
typedef short bf16x8 __attribute__((ext_vector_type(8)));
typedef float f32x4 __attribute__((ext_vector_type(4)));

__device__ inline u16 f2bf(float f) {  // RNE f32 -> bf16 (finite inputs)
  uint32_t u = __float_as_uint(f);
  return (u16)((u + 0x7fffu + ((u >> 16) & 1u)) >> 16);
}
__device__ inline float bflo2f(uint32_t u) { return __uint_as_float(u << 16); }
__device__ inline float bfhi2f(uint32_t u) { return __uint_as_float(u & 0xffff0000u); }

// ---------------- setup: convert x, convert weights, count degrees, B sentinel ----------------
// psiF: [l][o=256][k=128]; phiT: [l][n=128][k=256]; dpT: [n=128][k=128]

__global__ __launch_bounds__(256) void setup_kernel(
    const float* __restrict__ x, const float* __restrict__ psi_w,
    const float* __restrict__ phi_w, const float* __restrict__ dp_w,
    const int* __restrict__ dst, u16* __restrict__ xb, u16* __restrict__ psiF,
    u16* __restrict__ phiT, u16* __restrict__ dpT, int* __restrict__ deg,
    u16* __restrict__ Bb) {
  int b = blockIdx.x, t = threadIdx.x;
  if (b < 2500) {  // convert x: 2500*256*8 = 5.12M elements
    size_t i = ((size_t)b * 256 + t) * 8;
    float4 v0 = *(const float4*)(x + i);
    float4 v1 = *(const float4*)(x + i + 4);
    u16x8 o;
    o[0] = f2bf(v0.x); o[1] = f2bf(v0.y); o[2] = f2bf(v0.z); o[3] = f2bf(v0.w);
    o[4] = f2bf(v1.x); o[5] = f2bf(v1.y); o[6] = f2bf(v1.z); o[7] = f2bf(v1.w);
    *(u16x8*)(xb + i) = o;
  } else if (b < 3332) {  // weights: 832*256 = 212992
    int idx = (b - 2500) * 256 + t;
    if (idx < 98304) {
      int l = idx >> 15, r = idx & 32767, o = r >> 7, k = r & 127;
      int kk = k + ((o >= 128) ? 128 : 0);
      psiF[idx] = f2bf(psi_w[l * 32768 + kk * 128 + (o & 127)]);
    } else if (idx < 196608) {
      int j = idx - 98304;
      int l = j >> 15, r = j & 32767, n = r >> 8, k = r & 255;
      phiT[j] = f2bf(phi_w[l * 32768 + k * 128 + n]);
    } else {
      int j = idx - 196608;
      int n = j >> 7, k = j & 127;
      dpT[j] = f2bf(dp_w[k * 128 + n]);
    }
  } else if (b < 5832) {  // count degrees: 2500*256 = 640000
    int e = (b - 3332) * 256 + t;
    atomicAdd(&deg[dst[e]], 1);
  } else {  // sentinel row: Bb[N_NODES][*] = -inf (bf16 0xFF80)
    if (t < 64) ((uint32_t*)(Bb + (size_t)N_NODES * DD))[t] = 0xFF80FF80u;
  }
}

// ---------------- scan (single dispatch): each block self-computes its prefix base ----------

__global__ __launch_bounds__(256) void scan_all(const int* __restrict__ deg,
                                                int* __restrict__ offs,
                                                float* __restrict__ inv_deg,
                                                int* __restrict__ csr) {
  __shared__ int red[256];
  int b = blockIdx.x, t = threadIdx.x;
  if (b == 0 && t < 8) csr[N_EDGES + t] = N_NODES;  // sentinel pad for batched gather
  int base_n = b * 1024;
  int loc = 0;
  for (int i = t * 4; i < base_n; i += 1024) {
    int4 v = *(const int4*)(deg + i);
    loc += v.x + v.y + v.z + v.w;
  }
  red[t] = loc;
  __syncthreads();
  for (int o = 128; o > 0; o >>= 1) {
    if (t < o) red[t] += red[t + o];
    __syncthreads();
  }
  int base = red[0];
  __syncthreads();
  int idx = base_n + t * 4;
  int4 v = {0, 0, 0, 0};
  if (idx < N_NODES) v = *(const int4*)(deg + idx);
  int ts = v.x + v.y + v.z + v.w;
  red[t] = ts;
  __syncthreads();
  for (int o = 1; o < 256; o <<= 1) {
    int u = (t >= o) ? red[t - o] : 0;
    __syncthreads();
    red[t] += u;
    __syncthreads();
  }
  int excl = base + red[t] - ts;
  if (idx < N_NODES) {
    int4 ov;
    ov.x = excl;
    ov.y = excl + v.x;
    ov.z = ov.y + v.y;
    ov.w = ov.z + v.z;
    *(int4*)(offs + idx) = ov;
    float4 iv;
    iv.x = 1.0f / (float)(v.x > 1 ? v.x : 1);
    iv.y = 1.0f / (float)(v.y > 1 ? v.y : 1);
    iv.z = 1.0f / (float)(v.z > 1 ? v.z : 1);
    iv.w = 1.0f / (float)(v.w > 1 ? v.w : 1);
    *(float4*)(inv_deg + idx) = iv;
  }
  if (b == SB - 1 && t == 255) offs[N_NODES] = base + red[255];
}

// ---------------- fill CSR (blocks 625..3124) + psi layer 0 (blocks 0..624) ----------------
// [Ab | Bb] = X @ Wf[128x256]; independent of fill -> horizontal fusion, one dispatch.

__global__ __launch_bounds__(256, 3) void fill_psi0(
    const int* __restrict__ e_src, const int* __restrict__ e_dst,
    const int* __restrict__ offs, int* __restrict__ cnt, int* __restrict__ csr,
    const u16* __restrict__ X0, const u16* __restrict__ Wf, const float* __restrict__ bias,
    u16* __restrict__ Ab, u16* __restrict__ Bb) {
  __shared__ u16 Xs[64][72];
  __shared__ u16 Ws[256][72];
  if (blockIdx.x >= 625) {  // fill branch: 2500 blocks * 256 = 640000 edges
    int e = (blockIdx.x - 625) * 256 + threadIdx.x;
    int d = e_dst[e];
    int pos = offs[d] + atomicAdd(&cnt[d], 1);
    csr[pos] = e_src[e];
    return;
  }
  const int tid = threadIdx.x;
  const int row0 = blockIdx.x * 64;
  const int w = tid >> 6, lane = tid & 63;
  const int lm = lane & 15, lq = lane >> 4;

  f32x4 acc[16];
#pragma unroll
  for (int i = 0; i < 16; ++i) acc[i] = (f32x4){0.f, 0.f, 0.f, 0.f};

#pragma unroll
  for (int c = 0; c < 2; ++c) {
#pragma unroll
    for (int i = 0; i < 2; ++i) {
      int fi = tid + i * 256;
      int r = fi >> 3, k8 = (fi & 7) * 8;
      *(u16x8*)&Xs[r][k8] = *(const u16x8*)(X0 + (size_t)(row0 + r) * DD + c * 64 + k8);
    }
#pragma unroll
    for (int i = 0; i < 8; ++i) {
      int fi = tid + i * 256;
      int n = fi >> 3, k8 = (fi & 7) * 8;
      *(u16x8*)&Ws[n][k8] = *(const u16x8*)(Wf + (size_t)n * 128 + c * 64 + k8);
    }
    __syncthreads();
#pragma unroll
    for (int ks = 0; ks < 2; ++ks) {
      bf16x8 a = *(const bf16x8*)&Xs[w * 16 + lm][lq * 8 + ks * 32];
#pragma unroll
      for (int nt = 0; nt < 16; ++nt) {
        bf16x8 b = *(const bf16x8*)&Ws[nt * 16 + lm][lq * 8 + ks * 32];
        acc[nt] = __builtin_amdgcn_mfma_f32_16x16x32_bf16(a, b, acc[nt], 0, 0, 0);
      }
    }
    __syncthreads();
  }

  float bj[8];
#pragma unroll
  for (int nt = 0; nt < 8; ++nt) bj[nt] = bias[nt * 16 + lm];
#pragma unroll
  for (int r = 0; r < 4; ++r) {
    size_t grow = (size_t)(row0 + w * 16 + lq * 4 + r) * DD;
#pragma unroll
    for (int nt = 0; nt < 8; ++nt) Ab[grow + nt * 16 + lm] = f2bf(acc[nt][r] + bj[nt]);
#pragma unroll
    for (int nt = 0; nt < 8; ++nt) Bb[grow + nt * 16 + lm] = f2bf(acc[nt + 8][r]);
  }
}

// ---------------- aggregation: agg[i] = inv_deg[i] * sum_e relu(A[i] + B[src_e]) ----------

__global__ __launch_bounds__(256) void aggregate_bf16(
    const u16* __restrict__ A, const u16* __restrict__ B, const int* __restrict__ offs,
    const int* __restrict__ csr, const float* __restrict__ inv_deg, u16* __restrict__ agg) {
  int node = blockIdx.x * 4 + (threadIdx.x >> 6);
  int lane = threadIdx.x & 63;
  const int c2 = lane * 2;
  uint32_t au = *(const uint32_t*)(A + (size_t)node * DD + c2);
  float ax = bflo2f(au), ay = bfhi2f(au);
  int e = offs[node], ee = offs[node + 1];
  float sx = 0.f, sy = 0.f;
  for (; e < ee; e += 8) {
    int s[8];
#pragma unroll
    for (int i = 0; i < 8; ++i) {
      int v = csr[e + i];  // csr padded with sentinels past N_EDGES
      s[i] = (e + i < ee) ? v : N_NODES;  // sentinel row = -inf -> relu contributes 0
    }
    uint32_t bv[8];
#pragma unroll
    for (int i = 0; i < 8; ++i) bv[i] = *(const uint32_t*)(B + (size_t)s[i] * DD + c2);
#pragma unroll
    for (int i = 0; i < 8; ++i) {
      sx += fmaxf(ax + bflo2f(bv[i]), 0.f);
      sy += fmaxf(ay + bfhi2f(bv[i]), 0.f);
    }
  }
  float wg = inv_deg[node];
  uint32_t o = (uint32_t)f2bf(sx * wg) | ((uint32_t)f2bf(sy * wg) << 16);
  *(uint32_t*)(agg + (size_t)node * DD + c2) = o;
}

// ---------------- phi GEMM (K=256: x|agg) + residual, h kept in LDS;
// then: !LAST -> psi_{l+1} GEMM (2 halves, K=128 from LDS h) -> Ab/Bb
//        LAST -> dp GEMM (K=128 from LDS h) -> fp32 out

template <bool LAST>
__global__ __launch_bounds__(256, 2) void phi_psi(
    const u16* __restrict__ X0, const u16* __restrict__ X1, const u16* __restrict__ Wt,
    const float* __restrict__ bias, const u16* __restrict__ WN,
    const float* __restrict__ bN, u16* __restrict__ outB, u16* __restrict__ Ab,
    u16* __restrict__ Bb, float* __restrict__ outF) {
  __shared__ u16 Xs[2][64][72];
  __shared__ u16 Ws[128][72];
  const int tid = threadIdx.x;
  const int row0 = blockIdx.x * 64;
  const int w = tid >> 6, lane = tid & 63;
  const int lm = lane & 15, lq = lane >> 4;

  f32x4 acc[8];
#pragma unroll
  for (int i = 0; i < 8; ++i) acc[i] = (f32x4){0.f, 0.f, 0.f, 0.f};

#pragma unroll
  for (int c = 0; c < 4; ++c) {
    const u16* Xsrc = (c < 2) ? (X0 + c * 64) : (X1 + (c - 2) * 64);
#pragma unroll
    for (int i = 0; i < 2; ++i) {
      int fi = tid + i * 256;
      int r = fi >> 3, k8 = (fi & 7) * 8;
      *(u16x8*)&Xs[c & 1][r][k8] = *(const u16x8*)(Xsrc + (size_t)(row0 + r) * DD + k8);
    }
#pragma unroll
    for (int i = 0; i < 4; ++i) {
      int fi = tid + i * 256;
      int n = fi >> 3, k8 = (fi & 7) * 8;
      *(u16x8*)&Ws[n][k8] = *(const u16x8*)(Wt + (size_t)n * 256 + c * 64 + k8);
    }
    __syncthreads();
#pragma unroll
    for (int ks = 0; ks < 2; ++ks) {
      bf16x8 a = *(const bf16x8*)&Xs[c & 1][w * 16 + lm][lq * 8 + ks * 32];
#pragma unroll
      for (int nt = 0; nt < 8; ++nt) {
        bf16x8 b = *(const bf16x8*)&Ws[nt * 16 + lm][lq * 8 + ks * 32];
        acc[nt] = __builtin_amdgcn_mfma_f32_16x16x32_bf16(a, b, acc[nt], 0, 0, 0);
      }
    }
    __syncthreads();
  }

  // epilogue: v = relu(acc + bias) + x  (residual from global bf16 x, L2-hot)
  // h tile goes into LDS Xs (always); global xn write only if !LAST.
  float bj[8];
#pragma unroll
  for (int nt = 0; nt < 8; ++nt) bj[nt] = bias[nt * 16 + lm];
#pragma unroll
  for (int r = 0; r < 4; ++r) {
    int lrow = w * 16 + lq * 4 + r;
    size_t grow = (size_t)(row0 + lrow) * DD;
#pragma unroll
    for (int nt = 0; nt < 8; ++nt) {
      float res = bflo2f((uint32_t)X0[grow + nt * 16 + lm]);
      float v = fmaxf(acc[nt][r] + bj[nt], 0.f) + res;
      u16 hb = f2bf(v);
      Xs[nt >> 2][lrow][(nt & 3) * 16 + lm] = hb;
      if (!LAST) outB[grow + nt * 16 + lm] = hb;
    }
  }
  __syncthreads();

  if (!LAST) {
    // psi_{l+1}: [Ab|Bb] = h @ WN[256x128], two N-halves of 128
#pragma unroll
    for (int hf = 0; hf < 2; ++hf) {
      f32x4 acc2[8];
#pragma unroll
      for (int i = 0; i < 8; ++i) acc2[i] = (f32x4){0.f, 0.f, 0.f, 0.f};
#pragma unroll
      for (int c = 0; c < 2; ++c) {
#pragma unroll
        for (int i = 0; i < 4; ++i) {
          int fi = tid + i * 256;
          int n = fi >> 3, k8 = (fi & 7) * 8;
          *(u16x8*)&Ws[n][k8] =
              *(const u16x8*)(WN + (size_t)(hf * 128 + n) * DD + c * 64 + k8);
        }
        __syncthreads();
#pragma unroll
        for (int ks = 0; ks < 2; ++ks) {
          bf16x8 a = *(const bf16x8*)&Xs[c][w * 16 + lm][lq * 8 + ks * 32];
#pragma unroll
          for (int nt = 0; nt < 8; ++nt) {
            bf16x8 b = *(const bf16x8*)&Ws[nt * 16 + lm][lq * 8 + ks * 32];
            acc2[nt] = __builtin_amdgcn_mfma_f32_16x16x32_bf16(a, b, acc2[nt], 0, 0, 0);
          }
        }
        __syncthreads();
      }
      if (hf == 0) {
        float b2[8];
#pragma unroll
        for (int nt = 0; nt < 8; ++nt) b2[nt] = bN[nt * 16 + lm];
#pragma unroll
        for (int r = 0; r < 4; ++r) {
          size_t grow = (size_t)(row0 + w * 16 + lq * 4 + r) * DD;
#pragma unroll
          for (int nt = 0; nt < 8; ++nt)
            Ab[grow + nt * 16 + lm] = f2bf(acc2[nt][r] + b2[nt]);
        }
      } else {
#pragma unroll
        for (int r = 0; r < 4; ++r) {
          size_t grow = (size_t)(row0 + w * 16 + lq * 4 + r) * DD;
#pragma unroll
          for (int nt = 0; nt < 8; ++nt) Bb[grow + nt * 16 + lm] = f2bf(acc2[nt][r]);
        }
      }
    }
  } else {
    // dp: out = h @ WN[128x128] + bN (fp32)
    f32x4 acc2[8];
#pragma unroll
    for (int i = 0; i < 8; ++i) acc2[i] = (f32x4){0.f, 0.f, 0.f, 0.f};
#pragma unroll
    for (int c = 0; c < 2; ++c) {
#pragma unroll
      for (int i = 0; i < 4; ++i) {
        int fi = tid + i * 256;
        int n = fi >> 3, k8 = (fi & 7) * 8;
        *(u16x8*)&Ws[n][k8] = *(const u16x8*)(WN + (size_t)n * DD + c * 64 + k8);
      }
      __syncthreads();
#pragma unroll
      for (int ks = 0; ks < 2; ++ks) {
        bf16x8 a = *(const bf16x8*)&Xs[c][w * 16 + lm][lq * 8 + ks * 32];
#pragma unroll
        for (int nt = 0; nt < 8; ++nt) {
          bf16x8 b = *(const bf16x8*)&Ws[nt * 16 + lm][lq * 8 + ks * 32];
          acc2[nt] = __builtin_amdgcn_mfma_f32_16x16x32_bf16(a, b, acc2[nt], 0, 0, 0);
        }
      }
      __syncthreads();
    }
    float dj[8];
#pragma unroll
    for (int nt = 0; nt < 8; ++nt) dj[nt] = bN[nt * 16 + lm];
#pragma unroll
    for (int r = 0; r < 4; ++r) {
      size_t grow = (size_t)(row0 + w * 16 + lq * 4 + r) * DD;
#pragma unroll
      for (int nt = 0; nt < 8; ++nt) outF[grow + nt * 16 + lm] = acc2[nt][r] + dj[nt];
    }
  }
}

// ---------------- launch ----------------

static inline char* align256(char* p) {
  return (char*)(((uintptr_t)p + 255) & ~(uintptr_t)255);
}

extern "C" void kernel_launch(void* const* d_in, const int* in_sizes, int n_in,
                              void* d_out, int out_size, void* d_ws, size_t ws_size,
                              hipStream_t stream) {
  const float* x_in  = (const float*)d_in[0];
  const int*   ei    = (const int*)d_in[1];
  const float* psi_w = (const float*)d_in[2];
  const float* psi_b = (const float*)d_in[3];
  const float* phi_w = (const float*)d_in[4];
  const float* phi_b = (const float*)d_in[5];
  const float* dp_w  = (const float*)d_in[6];
  const float* dp_b  = (const float*)d_in[7];
  float* out = (float*)d_out;

  const int* e_src = ei;
  const int* e_dst = ei + N_EDGES;

  const size_t NF = (size_t)N_NODES * DD;

  char* p = (char*)d_ws;
  int* deg = (int*)p;         p += N_NODES * sizeof(int);
  int* cnt = (int*)p;         p = align256(p + N_NODES * sizeof(int));
  int* offs = (int*)p;        p = align256(p + (N_NODES + 1) * sizeof(int));
  int* csr = (int*)p;         p = align256(p + (N_EDGES + 8) * sizeof(int));
  float* inv_deg = (float*)p; p = align256(p + N_NODES * sizeof(float));
  u16* xb0 = (u16*)p;         p = align256(p + NF * sizeof(u16));
  u16* xb1 = (u16*)p;         p = align256(p + NF * sizeof(u16));
  u16* Ab = (u16*)p;          p = align256(p + NF * sizeof(u16));
  u16* Bb = (u16*)p;          p = align256(p + (NF + DD) * sizeof(u16));  // +1 sentinel row
  u16* aggb = (u16*)p;        p = align256(p + NF * sizeof(u16));
  u16* psiF = (u16*)p;        p = align256(p + 3 * 256 * 128 * sizeof(u16));
  u16* phiT = (u16*)p;        p = align256(p + 3 * 128 * 256 * sizeof(u16));
  u16* dpT = (u16*)p;         p = align256(p + 128 * 128 * sizeof(u16));

  hipMemsetAsync(deg, 0, 2 * N_NODES * sizeof(int), stream);  // deg + cnt contiguous

  setup_kernel<<<5833, 256, 0, stream>>>(x_in, psi_w, phi_w, dp_w, e_dst, xb0, psiF, phiT,
                                         dpT, deg, Bb);
  scan_all<<<SB, 256, 0, stream>>>(deg, offs, inv_deg, csr);
  fill_psi0<<<3125, 256, 0, stream>>>(e_src, e_dst, offs, cnt, csr, xb0, psiF,
                                      psi_b, Ab, Bb);

  const int GB = N_NODES / 64;  // 625 blocks

  u16* xbc = xb0;
  u16* xbn = xb1;
  for (int l = 0; l < LAYERS; ++l) {
    aggregate_bf16<<<N_NODES / 4, 256, 0, stream>>>(Ab, Bb, offs, csr, inv_deg, aggb);
    if (l < LAYERS - 1) {
      phi_psi<false><<<GB, 256, 0, stream>>>(
          xbc, aggb, phiT + (size_t)l * 32768, phi_b + l * DD,
          psiF + (size_t)(l + 1) * 32768, psi_b + (l + 1) * DD, xbn, Ab, Bb, nullptr);
    } else {
      phi_psi<true><<<GB, 256, 0, stream>>>(
          xbc, aggb, phiT + (size_t)l * 32768, phi_b + l * DD, dpT, dp_b, nullptr,
          nullptr, nullptr, out);
    }
    u16* t = xbc; xbc = xbn; xbn = t;
  }
}

// Round 8
// 277.712 us; speedup vs baseline: 5.0112x; 1.0367x over previous
//
#include <hip/hip_runtime.h>
#include <stdint.h>

#define N_NODES 40000
#define N_EDGES 640000
#define DD 128
#define LAYERS 3
#define SB 40  // scan blocks: 40 * 1024 >= N_NODES

typedef unsigned short u16;
typedef unsigned char u8;
typedef u16 u16x8 __attribute__((ext_vector_type(8)));
typedef short bf16x8 __attribute__((ext_vector_type(8)));
typedef float f32x4 __attribute__((ext_vector_type(4)));

__device__ inline u16 f2bf(float f) {  // RNE f32 -> bf16 (finite inputs)
  uint32_t u = __float_as_uint(f);
  return (u16)((u + 0x7fffu + ((u >> 16) & 1u)) >> 16);
}
__device__ inline float bflo2f(uint32_t u) { return __uint_as_float(u << 16); }
__device__ inline float bfhi2f(uint32_t u) { return __uint_as_float(u & 0xffff0000u); }
__device__ inline u8 f2fp8(float f) {  // f32 -> OCP e4m3fn via HW cvt
  return (u8)(__builtin_amdgcn_cvt_pk_fp8_f32(f, f, 0, false) & 0xFF);
}

// ---------------- setup: convert x, convert weights, count degrees, B sentinel ----------------
// psiF: [l][o=256][k=128]; phiT: [l][n=128][k=256]; dpT: [n=128][k=128]

__global__ __launch_bounds__(256) void setup_kernel(
    const float* __restrict__ x, const float* __restrict__ psi_w,
    const float* __restrict__ phi_w, const float* __restrict__ dp_w,
    const int* __restrict__ dst, u16* __restrict__ xb, u16* __restrict__ psiF,
    u16* __restrict__ phiT, u16* __restrict__ dpT, int* __restrict__ deg,
    u8* __restrict__ Bb) {
  int b = blockIdx.x, t = threadIdx.x;
  if (b < 2500) {  // convert x: 2500*256*8 = 5.12M elements
    size_t i = ((size_t)b * 256 + t) * 8;
    float4 v0 = *(const float4*)(x + i);
    float4 v1 = *(const float4*)(x + i + 4);
    u16x8 o;
    o[0] = f2bf(v0.x); o[1] = f2bf(v0.y); o[2] = f2bf(v0.z); o[3] = f2bf(v0.w);
    o[4] = f2bf(v1.x); o[5] = f2bf(v1.y); o[6] = f2bf(v1.z); o[7] = f2bf(v1.w);
    *(u16x8*)(xb + i) = o;
  } else if (b < 3332) {  // weights: 832*256 = 212992
    int idx = (b - 2500) * 256 + t;
    if (idx < 98304) {
      int l = idx >> 15, r = idx & 32767, o = r >> 7, k = r & 127;
      int kk = k + ((o >= 128) ? 128 : 0);
      psiF[idx] = f2bf(psi_w[l * 32768 + kk * 128 + (o & 127)]);
    } else if (idx < 196608) {
      int j = idx - 98304;
      int l = j >> 15, r = j & 32767, n = r >> 8, k = r & 255;
      phiT[j] = f2bf(phi_w[l * 32768 + k * 128 + n]);
    } else {
      int j = idx - 196608;
      int n = j >> 7, k = j & 127;
      dpT[j] = f2bf(dp_w[k * 128 + n]);
    }
  } else if (b < 5832) {  // count degrees: 2500*256 = 640000
    int e = (b - 3332) * 256 + t;
    atomicAdd(&deg[dst[e]], 1);
  } else {  // sentinel row: Bb[N_NODES][*] = 0xFE (-448 in e4m3fn) -> relu(A-448)=0
    if (t < 32) ((uint32_t*)(Bb + (size_t)N_NODES * DD))[t] = 0xFEFEFEFEu;
  }
}

// ---------------- scan (single dispatch): each block self-computes its prefix base ----------

__global__ __launch_bounds__(256) void scan_all(const int* __restrict__ deg,
                                                int* __restrict__ offs,
                                                float* __restrict__ inv_deg,
                                                int* __restrict__ csr) {
  __shared__ int red[256];
  int b = blockIdx.x, t = threadIdx.x;
  if (b == 0 && t < 16) csr[N_EDGES + t] = N_NODES;  // sentinel pad for batched gather
  int base_n = b * 1024;
  int loc = 0;
  for (int i = t * 4; i < base_n; i += 1024) {
    int4 v = *(const int4*)(deg + i);
    loc += v.x + v.y + v.z + v.w;
  }
  red[t] = loc;
  __syncthreads();
  for (int o = 128; o > 0; o >>= 1) {
    if (t < o) red[t] += red[t + o];
    __syncthreads();
  }
  int base = red[0];
  __syncthreads();
  int idx = base_n + t * 4;
  int4 v = {0, 0, 0, 0};
  if (idx < N_NODES) v = *(const int4*)(deg + idx);
  int ts = v.x + v.y + v.z + v.w;
  red[t] = ts;
  __syncthreads();
  for (int o = 1; o < 256; o <<= 1) {
    int u = (t >= o) ? red[t - o] : 0;
    __syncthreads();
    red[t] += u;
    __syncthreads();
  }
  int excl = base + red[t] - ts;
  if (idx < N_NODES) {
    int4 ov;
    ov.x = excl;
    ov.y = excl + v.x;
    ov.z = ov.y + v.y;
    ov.w = ov.z + v.z;
    *(int4*)(offs + idx) = ov;
    float4 iv;
    iv.x = 1.0f / (float)(v.x > 1 ? v.x : 1);
    iv.y = 1.0f / (float)(v.y > 1 ? v.y : 1);
    iv.z = 1.0f / (float)(v.z > 1 ? v.z : 1);
    iv.w = 1.0f / (float)(v.w > 1 ? v.w : 1);
    *(float4*)(inv_deg + idx) = iv;
  }
  if (b == SB - 1 && t == 255) offs[N_NODES] = base + red[255];
}

// ---------------- fill CSR (lean: no LDS, max occupancy) ----------------

__global__ void fill_csr_kernel(const int* __restrict__ src, const int* __restrict__ dst,
                                const int* __restrict__ offs, int* __restrict__ cnt,
                                int* __restrict__ csr) {
  int e = blockIdx.x * blockDim.x + threadIdx.x;
  if (e < N_EDGES) {
    int d = dst[e];
    int pos = offs[d] + atomicAdd(&cnt[d], 1);
    csr[pos] = src[e];
  }
}

// ---------------- psi layer 0: [Ab(bf16) | Bb(fp8)] = X @ Wf[128x256] ----------------

__global__ __launch_bounds__(256, 3) void gemm_psi0(const u16* __restrict__ X0,
                                                    const u16* __restrict__ Wf,
                                                    const float* __restrict__ bias,
                                                    u16* __restrict__ Ab, u8* __restrict__ Bb) {
  __shared__ u16 Xs[64][72];
  __shared__ u16 Ws[256][72];
  const int tid = threadIdx.x;
  const int row0 = blockIdx.x * 64;
  const int w = tid >> 6, lane = tid & 63;
  const int lm = lane & 15, lq = lane >> 4;

  f32x4 acc[16];
#pragma unroll
  for (int i = 0; i < 16; ++i) acc[i] = (f32x4){0.f, 0.f, 0.f, 0.f};

#pragma unroll
  for (int c = 0; c < 2; ++c) {
#pragma unroll
    for (int i = 0; i < 2; ++i) {
      int fi = tid + i * 256;
      int r = fi >> 3, k8 = (fi & 7) * 8;
      *(u16x8*)&Xs[r][k8] = *(const u16x8*)(X0 + (size_t)(row0 + r) * DD + c * 64 + k8);
    }
#pragma unroll
    for (int i = 0; i < 8; ++i) {
      int fi = tid + i * 256;
      int n = fi >> 3, k8 = (fi & 7) * 8;
      *(u16x8*)&Ws[n][k8] = *(const u16x8*)(Wf + (size_t)n * 128 + c * 64 + k8);
    }
    __syncthreads();
#pragma unroll
    for (int ks = 0; ks < 2; ++ks) {
      bf16x8 a = *(const bf16x8*)&Xs[w * 16 + lm][lq * 8 + ks * 32];
#pragma unroll
      for (int nt = 0; nt < 16; ++nt) {
        bf16x8 b = *(const bf16x8*)&Ws[nt * 16 + lm][lq * 8 + ks * 32];
        acc[nt] = __builtin_amdgcn_mfma_f32_16x16x32_bf16(a, b, acc[nt], 0, 0, 0);
      }
    }
    __syncthreads();
  }

  float bj[8];
#pragma unroll
  for (int nt = 0; nt < 8; ++nt) bj[nt] = bias[nt * 16 + lm];
#pragma unroll
  for (int r = 0; r < 4; ++r) {
    size_t grow = (size_t)(row0 + w * 16 + lq * 4 + r) * DD;
#pragma unroll
    for (int nt = 0; nt < 8; ++nt) Ab[grow + nt * 16 + lm] = f2bf(acc[nt][r] + bj[nt]);
#pragma unroll
    for (int nt = 0; nt < 8; ++nt) Bb[grow + nt * 16 + lm] = f2fp8(acc[nt + 8][r]);
  }
}

// ---------------- aggregation (fp8 B): one wave/node, half-wave/edge, lane = 4 channels ----

__global__ __launch_bounds__(256) void aggregate_fp8(
    const u16* __restrict__ A, const u8* __restrict__ B, const int* __restrict__ offs,
    const int* __restrict__ csr, const float* __restrict__ inv_deg, u16* __restrict__ agg) {
  int node = blockIdx.x * 4 + (threadIdx.x >> 6);
  int lane = threadIdx.x & 63;
  int half = lane >> 5;        // which edge of the pair
  int c4 = (lane & 31) * 4;    // 4 channels
  uint2 au = *(const uint2*)(A + (size_t)node * DD + c4);
  float a0 = bflo2f(au.x), a1 = bfhi2f(au.x), a2 = bflo2f(au.y), a3 = bfhi2f(au.y);
  int e = offs[node], ee = offs[node + 1];
  float s0 = 0.f, s1 = 0.f, s2 = 0.f, s3 = 0.f;
  for (int base = e + half; base < ee; base += 16) {
    int idx[8];
#pragma unroll
    for (int i = 0; i < 8; ++i) {
      int t = base + 2 * i;
      int v = csr[t];  // csr padded with 16 sentinels past N_EDGES
      idx[i] = (t < ee) ? v : N_NODES;  // sentinel row = -448 -> relu contributes 0
    }
    uint32_t bv[8];
#pragma unroll
    for (int i = 0; i < 8; ++i) bv[i] = *(const uint32_t*)(B + (size_t)idx[i] * DD + c4);
#pragma unroll
    for (int i = 0; i < 8; ++i) {
      s0 += fmaxf(a0 + __builtin_amdgcn_cvt_f32_fp8(bv[i], 0), 0.f);
      s1 += fmaxf(a1 + __builtin_amdgcn_cvt_f32_fp8(bv[i], 1), 0.f);
      s2 += fmaxf(a2 + __builtin_amdgcn_cvt_f32_fp8(bv[i], 2), 0.f);
      s3 += fmaxf(a3 + __builtin_amdgcn_cvt_f32_fp8(bv[i], 3), 0.f);
    }
  }
  s0 += __shfl_xor(s0, 32);
  s1 += __shfl_xor(s1, 32);
  s2 += __shfl_xor(s2, 32);
  s3 += __shfl_xor(s3, 32);
  if (half == 0) {
    float wg = inv_deg[node];
    uint2 o;
    o.x = (uint32_t)f2bf(s0 * wg) | ((uint32_t)f2bf(s1 * wg) << 16);
    o.y = (uint32_t)f2bf(s2 * wg) | ((uint32_t)f2bf(s3 * wg) << 16);
    *(uint2*)(agg + (size_t)node * DD + c4) = o;
  }
}

// ---------------- phi GEMM (K=256: x|agg) + residual, h kept in LDS;
// then: !LAST -> psi_{l+1} GEMM (2 halves, K=128 from LDS h) -> Ab(bf16)/Bb(fp8)
//        LAST -> dp GEMM (K=128 from LDS h) -> fp32 out

template <bool LAST>
__global__ __launch_bounds__(256, 3) void phi_psi(
    const u16* __restrict__ X0, const u16* __restrict__ X1, const u16* __restrict__ Wt,
    const float* __restrict__ bias, const u16* __restrict__ WN,
    const float* __restrict__ bN, u16* __restrict__ outB, u16* __restrict__ Ab,
    u8* __restrict__ Bb, float* __restrict__ outF) {
  __shared__ u16 Xs[2][64][72];
  __shared__ u16 Ws[128][72];
  const int tid = threadIdx.x;
  const int row0 = blockIdx.x * 64;
  const int w = tid >> 6, lane = tid & 63;
  const int lm = lane & 15, lq = lane >> 4;

  f32x4 acc[8];
#pragma unroll
  for (int i = 0; i < 8; ++i) acc[i] = (f32x4){0.f, 0.f, 0.f, 0.f};

#pragma unroll
  for (int c = 0; c < 4; ++c) {
    const u16* Xsrc = (c < 2) ? (X0 + c * 64) : (X1 + (c - 2) * 64);
#pragma unroll
    for (int i = 0; i < 2; ++i) {
      int fi = tid + i * 256;
      int r = fi >> 3, k8 = (fi & 7) * 8;
      *(u16x8*)&Xs[c & 1][r][k8] = *(const u16x8*)(Xsrc + (size_t)(row0 + r) * DD + k8);
    }
#pragma unroll
    for (int i = 0; i < 4; ++i) {
      int fi = tid + i * 256;
      int n = fi >> 3, k8 = (fi & 7) * 8;
      *(u16x8*)&Ws[n][k8] = *(const u16x8*)(Wt + (size_t)n * 256 + c * 64 + k8);
    }
    __syncthreads();
#pragma unroll
    for (int ks = 0; ks < 2; ++ks) {
      bf16x8 a = *(const bf16x8*)&Xs[c & 1][w * 16 + lm][lq * 8 + ks * 32];
#pragma unroll
      for (int nt = 0; nt < 8; ++nt) {
        bf16x8 b = *(const bf16x8*)&Ws[nt * 16 + lm][lq * 8 + ks * 32];
        acc[nt] = __builtin_amdgcn_mfma_f32_16x16x32_bf16(a, b, acc[nt], 0, 0, 0);
      }
    }
    __syncthreads();
  }

  // epilogue: v = relu(acc + bias) + x; h tile -> LDS Xs; global xn write only if !LAST
  float bj[8];
#pragma unroll
  for (int nt = 0; nt < 8; ++nt) bj[nt] = bias[nt * 16 + lm];
#pragma unroll
  for (int r = 0; r < 4; ++r) {
    int lrow = w * 16 + lq * 4 + r;
    size_t grow = (size_t)(row0 + lrow) * DD;
#pragma unroll
    for (int nt = 0; nt < 8; ++nt) {
      float res = bflo2f((uint32_t)X0[grow + nt * 16 + lm]);
      float v = fmaxf(acc[nt][r] + bj[nt], 0.f) + res;
      u16 hb = f2bf(v);
      Xs[nt >> 2][lrow][(nt & 3) * 16 + lm] = hb;
      if (!LAST) outB[grow + nt * 16 + lm] = hb;
    }
  }
  __syncthreads();

  if (!LAST) {
    // psi_{l+1}: [Ab|Bb] = h @ WN[256x128], two N-halves of 128
#pragma unroll
    for (int hf = 0; hf < 2; ++hf) {
      f32x4 acc2[8];
#pragma unroll
      for (int i = 0; i < 8; ++i) acc2[i] = (f32x4){0.f, 0.f, 0.f, 0.f};
#pragma unroll
      for (int c = 0; c < 2; ++c) {
#pragma unroll
        for (int i = 0; i < 4; ++i) {
          int fi = tid + i * 256;
          int n = fi >> 3, k8 = (fi & 7) * 8;
          *(u16x8*)&Ws[n][k8] =
              *(const u16x8*)(WN + (size_t)(hf * 128 + n) * DD + c * 64 + k8);
        }
        __syncthreads();
#pragma unroll
        for (int ks = 0; ks < 2; ++ks) {
          bf16x8 a = *(const bf16x8*)&Xs[c][w * 16 + lm][lq * 8 + ks * 32];
#pragma unroll
          for (int nt = 0; nt < 8; ++nt) {
            bf16x8 b = *(const bf16x8*)&Ws[nt * 16 + lm][lq * 8 + ks * 32];
            acc2[nt] = __builtin_amdgcn_mfma_f32_16x16x32_bf16(a, b, acc2[nt], 0, 0, 0);
          }
        }
        __syncthreads();
      }
      if (hf == 0) {
        float b2[8];
#pragma unroll
        for (int nt = 0; nt < 8; ++nt) b2[nt] = bN[nt * 16 + lm];
#pragma unroll
        for (int r = 0; r < 4; ++r) {
          size_t grow = (size_t)(row0 + w * 16 + lq * 4 + r) * DD;
#pragma unroll
          for (int nt = 0; nt < 8; ++nt)
            Ab[grow + nt * 16 + lm] = f2bf(acc2[nt][r] + b2[nt]);
        }
      } else {
#pragma unroll
        for (int r = 0; r < 4; ++r) {
          size_t grow = (size_t)(row0 + w * 16 + lq * 4 + r) * DD;
#pragma unroll
          for (int nt = 0; nt < 8; ++nt) Bb[grow + nt * 16 + lm] = f2fp8(acc2[nt][r]);
        }
      }
    }
  } else {
    // dp: out = h @ WN[128x128] + bN (fp32)
    f32x4 acc2[8];
#pragma unroll
    for (int i = 0; i < 8; ++i) acc2[i] = (f32x4){0.f, 0.f, 0.f, 0.f};
#pragma unroll
    for (int c = 0; c < 2; ++c) {
#pragma unroll
      for (int i = 0; i < 4; ++i) {
        int fi = tid + i * 256;
        int n = fi >> 3, k8 = (fi & 7) * 8;
        *(u16x8*)&Ws[n][k8] = *(const u16x8*)(WN + (size_t)n * DD + c * 64 + k8);
      }
      __syncthreads();
#pragma unroll
      for (int ks = 0; ks < 2; ++ks) {
        bf16x8 a = *(const bf16x8*)&Xs[c][w * 16 + lm][lq * 8 + ks * 32];
#pragma unroll
        for (int nt = 0; nt < 8; ++nt) {
          bf16x8 b = *(const bf16x8*)&Ws[nt * 16 + lm][lq * 8 + ks * 32];
          acc2[nt] = __builtin_amdgcn_mfma_f32_16x16x32_bf16(a, b, acc2[nt], 0, 0, 0);
        }
      }
      __syncthreads();
    }
    float dj[8];
#pragma unroll
    for (int nt = 0; nt < 8; ++nt) dj[nt] = bN[nt * 16 + lm];
#pragma unroll
    for (int r = 0; r < 4; ++r) {
      size_t grow = (size_t)(row0 + w * 16 + lq * 4 + r) * DD;
#pragma unroll
      for (int nt = 0; nt < 8; ++nt) outF[grow + nt * 16 + lm] = acc2[nt][r] + dj[nt];
    }
  }
}

// ---------------- launch ----------------

static inline char* align256(char* p) {
  return (char*)(((uintptr_t)p + 255) & ~(uintptr_t)255);
}

extern "C" void kernel_launch(void* const* d_in, const int* in_sizes, int n_in,
                              void* d_out, int out_size, void* d_ws, size_t ws_size,
                              hipStream_t stream) {
  const float* x_in  = (const float*)d_in[0];
  const int*   ei    = (const int*)d_in[1];
  const float* psi_w = (const float*)d_in[2];
  const float* psi_b = (const float*)d_in[3];
  const float* phi_w = (const float*)d_in[4];
  const float* phi_b = (const float*)d_in[5];
  const float* dp_w  = (const float*)d_in[6];
  const float* dp_b  = (const float*)d_in[7];
  float* out = (float*)d_out;

  const int* e_src = ei;
  const int* e_dst = ei + N_EDGES;

  const size_t NF = (size_t)N_NODES * DD;

  char* p = (char*)d_ws;
  int* deg = (int*)p;         p += N_NODES * sizeof(int);
  int* cnt = (int*)p;         p = align256(p + N_NODES * sizeof(int));
  int* offs = (int*)p;        p = align256(p + (N_NODES + 1) * sizeof(int));
  int* csr = (int*)p;         p = align256(p + (N_EDGES + 16) * sizeof(int));
  float* inv_deg = (float*)p; p = align256(p + N_NODES * sizeof(float));
  u16* xb0 = (u16*)p;         p = align256(p + NF * sizeof(u16));
  u16* xb1 = (u16*)p;         p = align256(p + NF * sizeof(u16));
  u16* Ab = (u16*)p;          p = align256(p + NF * sizeof(u16));
  u8* Bb = (u8*)p;            p = align256(p + (NF + DD) * sizeof(u8));  // +1 sentinel row
  u16* aggb = (u16*)p;        p = align256(p + NF * sizeof(u16));
  u16* psiF = (u16*)p;        p = align256(p + 3 * 256 * 128 * sizeof(u16));
  u16* phiT = (u16*)p;        p = align256(p + 3 * 128 * 256 * sizeof(u16));
  u16* dpT = (u16*)p;         p = align256(p + 128 * 128 * sizeof(u16));

  hipMemsetAsync(deg, 0, 2 * N_NODES * sizeof(int), stream);  // deg + cnt contiguous

  setup_kernel<<<5833, 256, 0, stream>>>(x_in, psi_w, phi_w, dp_w, e_dst, xb0, psiF, phiT,
                                         dpT, deg, Bb);
  scan_all<<<SB, 256, 0, stream>>>(deg, offs, inv_deg, csr);
  fill_csr_kernel<<<(N_EDGES + 255) / 256, 256, 0, stream>>>(e_src, e_dst, offs, cnt, csr);

  const int GB = N_NODES / 64;  // 625 blocks

  gemm_psi0<<<GB, 256, 0, stream>>>(xb0, psiF, psi_b, Ab, Bb);

  u16* xbc = xb0;
  u16* xbn = xb1;
  for (int l = 0; l < LAYERS; ++l) {
    aggregate_fp8<<<N_NODES / 4, 256, 0, stream>>>(Ab, Bb, offs, csr, inv_deg, aggb);
    if (l < LAYERS - 1) {
      phi_psi<false><<<GB, 256, 0, stream>>>(
          xbc, aggb, phiT + (size_t)l * 32768, phi_b + l * DD,
          psiF + (size_t)(l + 1) * 32768, psi_b + (l + 1) * DD, xbn, Ab, Bb, nullptr);
    } else {
      phi_psi<true><<<GB, 256, 0, stream>>>(
          xbc, aggb, phiT + (size_t)l * 32768, phi_b + l * DD, dpT, dp_b, nullptr,
          nullptr, nullptr, out);
    }
    u16* t = xbc; xbc = xbn; xbn = t;
  }
}